// Round 7
// baseline (6379.619 us; speedup 1.0000x reference)
//
#include <hip/hip_runtime.h>

#define S_LEN 8192
#define NH 16
#define NV 4
#define NB 512

typedef float v2f __attribute__((ext_vector_type(2)));

// ---------- DPP helpers ----------
template<int R>
__device__ __forceinline__ float rotf(float v) {
    return __int_as_float(__builtin_amdgcn_mov_dpp(__float_as_int(v), 0x120 + R, 0xF, 0xF, true));
}
__device__ __forceinline__ float qxor1(float v) {  // quad_perm [1,0,3,2]
    return __int_as_float(__builtin_amdgcn_mov_dpp(__float_as_int(v), 0xB1, 0xF, 0xF, true));
}
__device__ __forceinline__ float qxor2(float v) {  // quad_perm [2,3,0,1]
    return __int_as_float(__builtin_amdgcn_mov_dpp(__float_as_int(v), 0x4E, 0xF, 0xF, true));
}

__device__ __forceinline__ float fsig(float x) {   // known-good codegen: mul,exp,add,rcp
    return __builtin_amdgcn_rcpf(1.0f + __expf(-x));
}
__device__ __forceinline__ float frcp(float x) { return __builtin_amdgcn_rcpf(x); }
__device__ __forceinline__ float4 ld4(const float* p) { return *(const float4*)p; }

// Fill hp[8] = pairs of rotated h: hp[k] = { h[(j+sgn*2k)&15], h[(j+sgn*(2k+1))&15] }
#define FILL_HP(hp, h)                                   \
    do {                                                 \
        hp[0].x = (h);        hp[0].y = rotf<1>(h);      \
        hp[1].x = rotf<2>(h); hp[1].y = rotf<3>(h);      \
        hp[2].x = rotf<4>(h); hp[2].y = rotf<5>(h);      \
        hp[3].x = rotf<6>(h); hp[3].y = rotf<7>(h);      \
        hp[4].x = rotf<8>(h); hp[4].y = rotf<9>(h);      \
        hp[5].x = rotf<10>(h); hp[5].y = rotf<11>(h);    \
        hp[6].x = rotf<12>(h); hp[6].y = rotf<13>(h);    \
        hp[7].x = rotf<14>(h); hp[7].y = rotf<15>(h);    \
    } while (0)

// 16-dot as 8 packed pairs: 8 v_pk_fma + 1 v_pk_add + 1 v_add.  (R4's exact dot)
__device__ __forceinline__ float dot8p(const v2f* __restrict__ w, const v2f* hp, float start) {
    v2f a = __builtin_elementwise_fma(w[0], hp[0], (v2f){start, 0.0f});
    v2f b = w[1] * hp[1];
    a = __builtin_elementwise_fma(w[2], hp[2], a);
    b = __builtin_elementwise_fma(w[3], hp[3], b);
    a = __builtin_elementwise_fma(w[4], hp[4], a);
    b = __builtin_elementwise_fma(w[5], hp[5], b);
    a = __builtin_elementwise_fma(w[6], hp[6], a);
    b = __builtin_elementwise_fma(w[7], hp[7], b);
    v2f s = a + b;
    return s.x + s.y;
}

// 16 blocks x 512 threads (8 waves/block -> 1 block/CU -> 2 waves/SIMD).
// Each wave: 4 batch elements x 16 lanes. Body identical to R4 (best known).
__global__ __launch_bounds__(512) void rnn_kernel(
    const float* __restrict__ gt,
    const float* __restrict__ eWih, const float* __restrict__ eWhh,
    const float* __restrict__ ebih, const float* __restrict__ ebhh,
    const float* __restrict__ dWih, const float* __restrict__ dWhh,
    const float* __restrict__ dbih, const float* __restrict__ dbhh,
    const float* __restrict__ oW,  const float* __restrict__ ob,
    float* __restrict__ outs)                 // [NB][S_LEN][4] logit scratch
{
    const int j    = threadIdx.x & 15;        // hidden index within 16-lane row
    const int q    = j & 3;                   // out-gate this lane accumulates
    const int b    = blockIdx.x * 32 + (threadIdx.x >> 4);

    // DPP row_ror direction probe (direction-agnostic weight indexing).
    int probe = __builtin_amdgcn_mov_dpp(j, 0x121, 0xF, 0xF, true);
    const int sgn = (probe == ((j + 1) & 15)) ? 1 : -1;

    const float* gb = gt + (size_t)b * (NV * S_LEN);

    // ---------------- encoder weights (paired, rotated layout) ----------------
    v2f ewr[8], ewz[8], ewn[8];
#pragma unroll
    for (int p = 0; p < 8; ++p) {
        int k0 = (j + sgn * (2 * p)) & 15;
        int k1 = (j + sgn * (2 * p + 1)) & 15;
        ewr[p] = (v2f){eWhh[(0 * NH + j) * NH + k0], eWhh[(0 * NH + j) * NH + k1]};
        ewz[p] = (v2f){eWhh[(1 * NH + j) * NH + k0], eWhh[(1 * NH + j) * NH + k1]};
        ewn[p] = (v2f){eWhh[(2 * NH + j) * NH + k0], eWhh[(2 * NH + j) * NH + k1]};
    }
    float exr[NV], exz[NV], exn[NV];
#pragma unroll
    for (int v = 0; v < NV; ++v) {
        exr[v] = eWih[(0 * NH + j) * NV + v];
        exz[v] = eWih[(1 * NH + j) * NV + v];
        exn[v] = eWih[(2 * NH + j) * NV + v];
    }
    const float c_er  = ebih[j] + ebhh[j];
    const float c_ez  = ebih[NH + j] + ebhh[NH + j];
    const float c_ein = ebih[2 * NH + j];
    const float c_ehn = ebhh[2 * NH + j];

    float h = 0.0f;

    // h' = (1-z)*tanh(inn + r*hn) + z*h, parallel-blend form.
    auto gru = [&](float ar, float az, float hn, float inn) {
        float r  = fsig(ar);
        float z  = fsig(az);
        float t2 = fmaf(-2.0f, z, 2.0f);         // 2(1-z)   (z-chain, parallel to r)
        float tb = fmaf(z, h, z - 1.0f);         // z*h + z - 1
        float y  = fmaf(r, hn, inn);
        float w2 = frcp(1.0f + __expf(-2.0f * y));
        h = fmaf(w2, t2, tb);                    // (2w2-1)(1-z) + z*h
    };

    auto estep = [&](float x0, float x1, float x2, float x3) {
        float xr = fmaf(exr[0], x0, fmaf(exr[1], x1, fmaf(exr[2], x2, fmaf(exr[3], x3, c_er))));
        float xz = fmaf(exz[0], x0, fmaf(exz[1], x1, fmaf(exz[2], x2, fmaf(exz[3], x3, c_ez))));
        float xn = fmaf(exn[0], x0, fmaf(exn[1], x1, fmaf(exn[2], x2, fmaf(exn[3], x3, c_ein))));
        v2f hp[8];
        FILL_HP(hp, h);
        float ar = dot8p(ewr, hp, xr);
        float az = dot8p(ewz, hp, xz);
        float hn = dot8p(ewn, hp, c_ehn);
        gru(ar, az, hn, xn);
    };

    // ---------------- encoder loop ----------------
    {
        float4 A0 = ld4(gb + 0 * S_LEN), A1 = ld4(gb + 1 * S_LEN),
               A2 = ld4(gb + 2 * S_LEN), A3 = ld4(gb + 3 * S_LEN);
        float4 B0 = ld4(gb + 0 * S_LEN + 4), B1 = ld4(gb + 1 * S_LEN + 4),
               B2 = ld4(gb + 2 * S_LEN + 4), B3 = ld4(gb + 3 * S_LEN + 4);
        for (int t = 0; t < S_LEN; t += 8) {
            estep(A0.x, A1.x, A2.x, A3.x);
            estep(A0.y, A1.y, A2.y, A3.y);
            estep(A0.z, A1.z, A2.z, A3.z);
            estep(A0.w, A1.w, A2.w, A3.w);
            int ta = t + 8;  if (ta > S_LEN - 4) ta = S_LEN - 4;
            A0 = ld4(gb + 0 * S_LEN + ta); A1 = ld4(gb + 1 * S_LEN + ta);
            A2 = ld4(gb + 2 * S_LEN + ta); A3 = ld4(gb + 3 * S_LEN + ta);
            estep(B0.x, B1.x, B2.x, B3.x);
            estep(B0.y, B1.y, B2.y, B3.y);
            estep(B0.z, B1.z, B2.z, B3.z);
            estep(B0.w, B1.w, B2.w, B3.w);
            int tb2 = t + 12; if (tb2 > S_LEN - 4) tb2 = S_LEN - 4;
            B0 = ld4(gb + 0 * S_LEN + tb2); B1 = ld4(gb + 1 * S_LEN + tb2);
            B2 = ld4(gb + 2 * S_LEN + tb2); B3 = ld4(gb + 3 * S_LEN + tb2);
        }
    }

    // ---------------- decoder weights ----------------
    v2f dwr[8], dwz[8], dwn[8], ow2[8];
#pragma unroll
    for (int p = 0; p < 8; ++p) {
        int k0 = (j + sgn * (2 * p)) & 15;
        int k1 = (j + sgn * (2 * p + 1)) & 15;
        dwr[p] = (v2f){dWhh[(0 * NH + j) * NH + k0], dWhh[(0 * NH + j) * NH + k1]};
        dwz[p] = (v2f){dWhh[(1 * NH + j) * NH + k0], dWhh[(1 * NH + j) * NH + k1]};
        dwn[p] = (v2f){dWhh[(2 * NH + j) * NH + k0], dWhh[(2 * NH + j) * NH + k1]};
        ow2[p] = (v2f){oW[q * NH + k0], oW[q * NH + k1]};
    }
    const float bR  = dbih[j] + dbhh[j];
    const float bZ  = dbih[NH + j] + dbhh[NH + j];
    const float bNi = dbih[2 * NH + j];
    const float bHn = dbhh[2 * NH + j];
    // per-class one-hot constants, REGISTER order m (class = m ^ q):
    float KRr[NV], KZr[NV], KNr[NV];
#pragma unroll
    for (int m = 0; m < NV; ++m) {
        int c = m ^ q;
        KRr[m] = dWih[(0 * NH + j) * NV + c];
        KZr[m] = dWih[(1 * NH + j) * NV + c];
        KNr[m] = dWih[(2 * NH + j) * NV + c];
    }
    const float obq = ob[q];

    int oidx = (b << 15) + q;       // (b*S_LEN + 0)*4 + q
    const bool storer = (j < 4);    // quad 0 of each row stores out[0..3]

    // dstep: gathers h'(t-1); GRU dots + out-head of step t-1; stores logits of t-1;
    // argmax feedback selects one-hot constants; updates h.
    auto dstep = [&]() {
        v2f hp[8];
        FILL_HP(hp, h);
        float ar = dot8p(dwr, hp, bR);
        float az = dot8p(dwz, hp, bZ);
        float hn = dot8p(dwn, hp, bHn);
        float oa = dot8p(ow2, hp, obq);          // out[q] of step t-1
        if (storer) outs[oidx] = oa;
        oidx += 4;
        float o_b = qxor1(oa);                   // out[q^1]
        float o_c = qxor2(oa);                   // out[q^2]
        float o_d = qxor2(o_b);                  // out[q^3]
        bool cA = o_b > oa;  float mA = fmaxf(oa, o_b);
        bool cB = o_d > o_c; float mB = fmaxf(o_c, o_d);
        bool hi = mB > mA;
        float KR = hi ? (cB ? KRr[3] : KRr[2]) : (cA ? KRr[1] : KRr[0]);
        float KZ = hi ? (cB ? KZr[3] : KZr[2]) : (cA ? KZr[1] : KZr[0]);
        float KN = hi ? (cB ? KNr[3] : KNr[2]) : (cA ? KNr[1] : KNr[0]);
        gru(ar + KR, az + KZ, hn, bNi + KN);
    };

    // ---------------- decoder loop (no gt reads at all) ----------------
    {
        // t = 0: x0 = zeros, no previous logits
        v2f hp[8];
        FILL_HP(hp, h);
        float ar = dot8p(dwr, hp, bR);
        float az = dot8p(dwz, hp, bZ);
        float hn = dot8p(dwn, hp, bHn);
        gru(ar, az, hn, bNi);
    }
    for (int u = 0; u < S_LEN - 4; u += 4) {     // 8188 steps (t = 1..8188)
        dstep(); dstep(); dstep(); dstep();
    }
    dstep(); dstep(); dstep();                   // t = 8189..8191

    // tail: logits of final step (t = S-1)
    {
        v2f hp[8];
        FILL_HP(hp, h);
        float oa = dot8p(ow2, hp, obq);
        if (storer) outs[oidx] = oa;
    }
}

// Epilogue: NLL over all (b,t) from stored logits + gt targets; zero the scratch
// (restores the required all-zero output_batch). 4096 blocks x 1024 threads.
__global__ __launch_bounds__(1024) void loss_kernel(
    const float* __restrict__ gt, float* __restrict__ outs, float* __restrict__ loss)
{
    int tid = blockIdx.x * 1024 + threadIdx.x;   // over NB*S_LEN
    int t = tid & (S_LEN - 1);
    int b = tid >> 13;
    float4 o = *(const float4*)(outs + (size_t)tid * 4);
    const float* g = gt + (size_t)b * (NV * S_LEN) + t;
    float p0 = g[0], p1 = g[S_LEN], p2 = g[2 * S_LEN], p3 = g[3 * S_LEN];
    int tg = (p1 > p0) ? 1 : 0;  float bm = fmaxf(p0, p1);
    tg = (p2 > bm) ? 2 : tg;     bm = fmaxf(p2, bm);
    tg = (p3 > bm) ? 3 : tg;
    float vt = (tg & 1) ? ((tg & 2) ? o.w : o.y) : ((tg & 2) ? o.z : o.x);
    float mx = fmaxf(fmaxf(o.x, o.y), fmaxf(o.z, o.w));
    float ss = __expf(o.x - mx) + __expf(o.y - mx) + __expf(o.z - mx) + __expf(o.w - mx);
    float v  = (mx - vt) + __logf(ss);
    *(float4*)(outs + (size_t)tid * 4) = make_float4(0.f, 0.f, 0.f, 0.f);
    // wave reduce
#pragma unroll
    for (int d = 1; d < 64; d <<= 1) v += __shfl_xor(v, d, 64);
    __shared__ float sm[16];
    int w = threadIdx.x >> 6;
    if ((threadIdx.x & 63) == 0) sm[w] = v;
    __syncthreads();
    if (threadIdx.x < 16) {
        float s = sm[threadIdx.x];
#pragma unroll
        for (int d = 1; d < 16; d <<= 1) s += __shfl_xor(s, d, 64);
        if (threadIdx.x == 0) atomicAdd(loss, s * (1.0f / NB));
    }
}

extern "C" void kernel_launch(void* const* d_in, const int* in_sizes, int n_in,
                              void* d_out, int out_size, void* d_ws, size_t ws_size,
                              hipStream_t stream) {
    (void)in_sizes; (void)n_in; (void)d_ws; (void)ws_size; (void)out_size;
    const float* gt   = (const float*)d_in[0];
    const float* eWih = (const float*)d_in[1];
    const float* eWhh = (const float*)d_in[2];
    const float* ebih = (const float*)d_in[3];
    const float* ebhh = (const float*)d_in[4];
    const float* dWih = (const float*)d_in[5];
    const float* dWhh = (const float*)d_in[6];
    const float* dbih = (const float*)d_in[7];
    const float* dbhh = (const float*)d_in[8];
    const float* oW   = (const float*)d_in[9];
    const float* ob   = (const float*)d_in[10];

    float* out  = (float*)d_out;       // out[0] = loss
    float* outs = out + 1;             // [NB][S_LEN][4] logit scratch == output_batch region
    hipMemsetAsync(d_out, 0, sizeof(float), stream);   // zero loss only
    // 16 blocks x 512 threads: 8 waves/block -> 1 block/CU -> 2 waves/SIMD.
    rnn_kernel<<<16, 512, 0, stream>>>(gt, eWih, eWhh, ebih, ebhh,
                                       dWih, dWhh, dbih, dbhh, oW, ob, outs);
    loss_kernel<<<(NB * S_LEN) / 1024, 1024, 0, stream>>>(gt, outs, out);
}

// Round 9
// 3704.199 us; speedup vs baseline: 1.7223x; 1.7223x over previous
//
#include <hip/hip_runtime.h>

#define S_LEN 8192
#define NH 16
#define NV 4
#define NB 512

typedef _Float16 h2 __attribute__((ext_vector_type(2)));

// ---------- DPP helpers ----------
template<int R>
__device__ __forceinline__ float rotf(float v) {
    return __int_as_float(__builtin_amdgcn_mov_dpp(__float_as_int(v), 0x120 + R, 0xF, 0xF, true));
}
template<int R>
__device__ __forceinline__ h2 roth(h2 v) {    // row_ror:R on a packed half2 reg
    int i;
    __builtin_memcpy(&i, &v, 4);
    i = __builtin_amdgcn_mov_dpp(i, 0x120 + R, 0xF, 0xF, true);
    h2 o;
    __builtin_memcpy(&o, &i, 4);
    return o;
}
__device__ __forceinline__ float qxor1(float v) {  // quad_perm [1,0,3,2]
    return __int_as_float(__builtin_amdgcn_mov_dpp(__float_as_int(v), 0xB1, 0xF, 0xF, true));
}
__device__ __forceinline__ float qxor2(float v) {  // quad_perm [2,3,0,1]
    return __int_as_float(__builtin_amdgcn_mov_dpp(__float_as_int(v), 0x4E, 0xF, 0xF, true));
}

__device__ __forceinline__ float fsig(float x) {   // mul,exp,add,rcp
    return __builtin_amdgcn_rcpf(1.0f + __expf(-x));
}
__device__ __forceinline__ float frcp(float x) { return __builtin_amdgcn_rcpf(x); }
__device__ __forceinline__ float4 ld4(const float* p) { return *(const float4*)p; }

// Pack (h, rot1(h)) to half2 via v_cvt_pkrtz_f16_f32, bitcast to h2.
__device__ __forceinline__ h2 pkh(float a, float b) {
    auto t = __builtin_amdgcn_cvt_pkrtz(a, b);   // __fp16 ext_vector(2)
    h2 o;
    __builtin_memcpy(&o, &t, 4);
    return o;
}

// hp[k] = packed (h[(j+sgn*2k)&15], h[(j+sgn*(2k+1))&15]) as half2.
// Built from ONE cvt_pkrtz + 8 DPP movs total.
#define FILL_HP16(hp, h)                                      \
    do {                                                      \
        h2 p0_ = pkh((h), rotf<1>(h));                        \
        hp[0] = p0_;                                          \
        hp[1] = roth<2>(p0_);                                 \
        hp[2] = roth<4>(p0_);                                 \
        hp[3] = roth<6>(p0_);                                 \
        hp[4] = roth<8>(p0_);                                 \
        hp[5] = roth<10>(p0_);                                \
        hp[6] = roth<12>(p0_);                                \
        hp[7] = roth<14>(p0_);                                \
    } while (0)

// 16-dot via full-rate v_dot2_f32_f16: 8 dot2 + 1 add, two chains of depth 4.
__device__ __forceinline__ float dotd2(const h2* __restrict__ w, const h2* hp, float start) {
    float a = __builtin_amdgcn_fdot2(w[0], hp[0], start, false);
    float b = __builtin_amdgcn_fdot2(w[1], hp[1], 0.0f, false);
    a = __builtin_amdgcn_fdot2(w[2], hp[2], a, false);
    b = __builtin_amdgcn_fdot2(w[3], hp[3], b, false);
    a = __builtin_amdgcn_fdot2(w[4], hp[4], a, false);
    b = __builtin_amdgcn_fdot2(w[5], hp[5], b, false);
    a = __builtin_amdgcn_fdot2(w[6], hp[6], a, false);
    b = __builtin_amdgcn_fdot2(w[7], hp[7], b, false);
    return a + b;
}

// 128 blocks x 64 threads. Each wave: 4 batch elements x 16 lanes (R4 structure).
__global__ __launch_bounds__(64, 1) void rnn_kernel(
    const float* __restrict__ gt,
    const float* __restrict__ eWih, const float* __restrict__ eWhh,
    const float* __restrict__ ebih, const float* __restrict__ ebhh,
    const float* __restrict__ dWih, const float* __restrict__ dWhh,
    const float* __restrict__ dbih, const float* __restrict__ dbhh,
    const float* __restrict__ oW,  const float* __restrict__ ob,
    float* __restrict__ outs)                 // [NB][S_LEN][4] logit scratch
{
    const int lane = threadIdx.x;
    const int j    = lane & 15;
    const int q    = j & 3;
    const int b    = blockIdx.x * 4 + (lane >> 4);

    // DPP row_ror direction probe (direction-agnostic weight indexing).
    int probe = __builtin_amdgcn_mov_dpp(j, 0x121, 0xF, 0xF, true);
    const int sgn = (probe == ((j + 1) & 15)) ? 1 : -1;

    const float* gb = gt + (size_t)b * (NV * S_LEN);

    // ---------------- encoder weights (paired f16, rotated layout) ----------------
    h2 ewr[8], ewz[8], ewn[8];
#pragma unroll
    for (int p = 0; p < 8; ++p) {
        int k0 = (j + sgn * (2 * p)) & 15;
        int k1 = (j + sgn * (2 * p + 1)) & 15;
        ewr[p] = (h2){(_Float16)eWhh[(0 * NH + j) * NH + k0], (_Float16)eWhh[(0 * NH + j) * NH + k1]};
        ewz[p] = (h2){(_Float16)eWhh[(1 * NH + j) * NH + k0], (_Float16)eWhh[(1 * NH + j) * NH + k1]};
        ewn[p] = (h2){(_Float16)eWhh[(2 * NH + j) * NH + k0], (_Float16)eWhh[(2 * NH + j) * NH + k1]};
    }
    float exr[NV], exz[NV], exn[NV];
#pragma unroll
    for (int v = 0; v < NV; ++v) {
        exr[v] = eWih[(0 * NH + j) * NV + v];
        exz[v] = eWih[(1 * NH + j) * NV + v];
        exn[v] = eWih[(2 * NH + j) * NV + v];
    }
    const float c_er  = ebih[j] + ebhh[j];
    const float c_ez  = ebih[NH + j] + ebhh[NH + j];
    const float c_ein = ebih[2 * NH + j];
    const float c_ehn = ebhh[2 * NH + j];

    float h = 0.0f;

    // h' = (1-z)*tanh(inn + r*hn) + z*h, parallel-blend form (R4).
    auto gru = [&](float ar, float az, float hn, float inn) {
        float r  = fsig(ar);
        float z  = fsig(az);
        float t2 = fmaf(-2.0f, z, 2.0f);
        float tb = fmaf(z, h, z - 1.0f);
        float y  = fmaf(r, hn, inn);
        float w2 = frcp(1.0f + __expf(-2.0f * y));
        h = fmaf(w2, t2, tb);
    };

    auto estep = [&](float x0, float x1, float x2, float x3) {
        float xr = fmaf(exr[0], x0, fmaf(exr[1], x1, fmaf(exr[2], x2, fmaf(exr[3], x3, c_er))));
        float xz = fmaf(exz[0], x0, fmaf(exz[1], x1, fmaf(exz[2], x2, fmaf(exz[3], x3, c_ez))));
        float xn = fmaf(exn[0], x0, fmaf(exn[1], x1, fmaf(exn[2], x2, fmaf(exn[3], x3, c_ein))));
        h2 hp[8];
        FILL_HP16(hp, h);
        float ar = dotd2(ewr, hp, xr);
        float az = dotd2(ewz, hp, xz);
        float hn = dotd2(ewn, hp, c_ehn);
        gru(ar, az, hn, xn);
    };

    // ---------------- encoder loop ----------------
    {
        float4 A0 = ld4(gb + 0 * S_LEN), A1 = ld4(gb + 1 * S_LEN),
               A2 = ld4(gb + 2 * S_LEN), A3 = ld4(gb + 3 * S_LEN);
        float4 B0 = ld4(gb + 0 * S_LEN + 4), B1 = ld4(gb + 1 * S_LEN + 4),
               B2 = ld4(gb + 2 * S_LEN + 4), B3 = ld4(gb + 3 * S_LEN + 4);
        for (int t = 0; t < S_LEN; t += 8) {
            estep(A0.x, A1.x, A2.x, A3.x);
            estep(A0.y, A1.y, A2.y, A3.y);
            estep(A0.z, A1.z, A2.z, A3.z);
            estep(A0.w, A1.w, A2.w, A3.w);
            int ta = t + 8;  if (ta > S_LEN - 4) ta = S_LEN - 4;
            A0 = ld4(gb + 0 * S_LEN + ta); A1 = ld4(gb + 1 * S_LEN + ta);
            A2 = ld4(gb + 2 * S_LEN + ta); A3 = ld4(gb + 3 * S_LEN + ta);
            estep(B0.x, B1.x, B2.x, B3.x);
            estep(B0.y, B1.y, B2.y, B3.y);
            estep(B0.z, B1.z, B2.z, B3.z);
            estep(B0.w, B1.w, B2.w, B3.w);
            int tb2 = t + 12; if (tb2 > S_LEN - 4) tb2 = S_LEN - 4;
            B0 = ld4(gb + 0 * S_LEN + tb2); B1 = ld4(gb + 1 * S_LEN + tb2);
            B2 = ld4(gb + 2 * S_LEN + tb2); B3 = ld4(gb + 3 * S_LEN + tb2);
        }
    }

    // ---------------- decoder weights ----------------
    h2 dwr[8], dwz[8], dwn[8], ow2[8];
#pragma unroll
    for (int p = 0; p < 8; ++p) {
        int k0 = (j + sgn * (2 * p)) & 15;
        int k1 = (j + sgn * (2 * p + 1)) & 15;
        dwr[p] = (h2){(_Float16)dWhh[(0 * NH + j) * NH + k0], (_Float16)dWhh[(0 * NH + j) * NH + k1]};
        dwz[p] = (h2){(_Float16)dWhh[(1 * NH + j) * NH + k0], (_Float16)dWhh[(1 * NH + j) * NH + k1]};
        dwn[p] = (h2){(_Float16)dWhh[(2 * NH + j) * NH + k0], (_Float16)dWhh[(2 * NH + j) * NH + k1]};
        ow2[p] = (h2){(_Float16)oW[q * NH + k0], (_Float16)oW[q * NH + k1]};
    }
    const float bR  = dbih[j] + dbhh[j];
    const float bZ  = dbih[NH + j] + dbhh[NH + j];
    const float bNi = dbih[2 * NH + j];
    const float bHn = dbhh[2 * NH + j];
    // per-class one-hot constants, REGISTER order m (class = m ^ q); bNi folded into KN:
    float KRr[NV], KZr[NV], KNr[NV];
#pragma unroll
    for (int m = 0; m < NV; ++m) {
        int c = m ^ q;
        KRr[m] = dWih[(0 * NH + j) * NV + c];
        KZr[m] = dWih[(1 * NH + j) * NV + c];
        KNr[m] = bNi + dWih[(2 * NH + j) * NV + c];
    }
    const float obq = ob[q];

    int oidx = (b << 15) + q;       // (b*S_LEN + 0)*4 + q  -- [B][S][4] layout
    const bool storer = (j < 4);    // quad 0 of each row stores out[0..3]

    auto dstep = [&]() {
        h2 hp[8];
        FILL_HP16(hp, h);
        float ar = dotd2(dwr, hp, bR);
        float az = dotd2(dwz, hp, bZ);
        float hn = dotd2(dwn, hp, bHn);
        float oa = dotd2(ow2, hp, obq);          // out[q] of step t-1
        if (storer) outs[oidx] = oa;
        oidx += 4;
        float o_b = qxor1(oa);                   // out[q^1]
        float o_c = qxor2(oa);                   // out[q^2]
        float o_d = qxor2(o_b);                  // out[q^3]
        bool cA = o_b > oa;  float mA = fmaxf(oa, o_b);
        bool cB = o_d > o_c; float mB = fmaxf(o_c, o_d);
        bool hi = mB > mA;
        float KR = hi ? (cB ? KRr[3] : KRr[2]) : (cA ? KRr[1] : KRr[0]);
        float KZ = hi ? (cB ? KZr[3] : KZr[2]) : (cA ? KZr[1] : KZr[0]);
        float KN = hi ? (cB ? KNr[3] : KNr[2]) : (cA ? KNr[1] : KNr[0]);
        gru(ar + KR, az + KZ, hn, KN);
    };

    // ---------------- decoder loop (no gt reads) ----------------
    {
        // t = 0: x0 = zeros, no previous logits
        h2 hp[8];
        FILL_HP16(hp, h);
        float ar = dotd2(dwr, hp, bR);
        float az = dotd2(dwz, hp, bZ);
        float hn = dotd2(dwn, hp, bHn);
        gru(ar, az, hn, bNi);
    }
    for (int u = 0; u < S_LEN - 4; u += 4) {     // t = 1..8188
        dstep(); dstep(); dstep(); dstep();
    }
    dstep(); dstep(); dstep();                   // t = 8189..8191

    // tail: logits of final step (t = S-1)
    {
        h2 hp[8];
        FILL_HP16(hp, h);
        float oa = dotd2(ow2, hp, obq);
        if (storer) outs[oidx] = oa;
    }
}

// Epilogue: NLL over all (b,t) from stored logits + gt targets; zero the scratch
// (restores the required all-zero output_batch). 4096 blocks x 1024 threads.
__global__ __launch_bounds__(1024) void loss_kernel(
    const float* __restrict__ gt, float* __restrict__ outs, float* __restrict__ loss)
{
    int tid = blockIdx.x * 1024 + threadIdx.x;   // over NB*S_LEN
    int t = tid & (S_LEN - 1);
    int b = tid >> 13;
    float4 o = *(const float4*)(outs + (size_t)tid * 4);
    const float* g = gt + (size_t)b * (NV * S_LEN) + t;
    float p0 = g[0], p1 = g[S_LEN], p2 = g[2 * S_LEN], p3 = g[3 * S_LEN];
    int tg = (p1 > p0) ? 1 : 0;  float bm = fmaxf(p0, p1);
    tg = (p2 > bm) ? 2 : tg;     bm = fmaxf(p2, bm);
    tg = (p3 > bm) ? 3 : tg;
    float vt = (tg & 1) ? ((tg & 2) ? o.w : o.y) : ((tg & 2) ? o.z : o.x);
    float mx = fmaxf(fmaxf(o.x, o.y), fmaxf(o.z, o.w));
    float ss = __expf(o.x - mx) + __expf(o.y - mx) + __expf(o.z - mx) + __expf(o.w - mx);
    float v  = (mx - vt) + __logf(ss);
    *(float4*)(outs + (size_t)tid * 4) = make_float4(0.f, 0.f, 0.f, 0.f);
#pragma unroll
    for (int d = 1; d < 64; d <<= 1) v += __shfl_xor(v, d, 64);
    __shared__ float sm[16];
    int w = threadIdx.x >> 6;
    if ((threadIdx.x & 63) == 0) sm[w] = v;
    __syncthreads();
    if (threadIdx.x < 16) {
        float s = sm[threadIdx.x];
#pragma unroll
        for (int d = 1; d < 16; d <<= 1) s += __shfl_xor(s, d, 64);
        if (threadIdx.x == 0) atomicAdd(loss, s * (1.0f / NB));
    }
}

extern "C" void kernel_launch(void* const* d_in, const int* in_sizes, int n_in,
                              void* d_out, int out_size, void* d_ws, size_t ws_size,
                              hipStream_t stream) {
    (void)in_sizes; (void)n_in; (void)d_ws; (void)ws_size; (void)out_size;
    const float* gt   = (const float*)d_in[0];
    const float* eWih = (const float*)d_in[1];
    const float* eWhh = (const float*)d_in[2];
    const float* ebih = (const float*)d_in[3];
    const float* ebhh = (const float*)d_in[4];
    const float* dWih = (const float*)d_in[5];
    const float* dWhh = (const float*)d_in[6];
    const float* dbih = (const float*)d_in[7];
    const float* dbhh = (const float*)d_in[8];
    const float* oW   = (const float*)d_in[9];
    const float* ob   = (const float*)d_in[10];

    float* out  = (float*)d_out;       // out[0] = loss
    float* outs = out + 1;             // [NB][S_LEN][4] logit scratch == output_batch region
    (void)hipMemsetAsync(d_out, 0, sizeof(float), stream);   // zero loss only
    rnn_kernel<<<NB / 4, 64, 0, stream>>>(gt, eWih, eWhh, ebih, ebhh,
                                          dWih, dWhh, dbih, dbhh, oW, ob, outs);
    loss_kernel<<<(NB * S_LEN) / 1024, 1024, 0, stream>>>(gt, outs, out);
}